// Round 7
// baseline (375.845 us; speedup 1.0000x reference)
//
#include <hip/hip_runtime.h>
#include <hip/hip_bf16.h>
#include <cstddef>

typedef _Float16 h2 __attribute__((ext_vector_type(2)));
typedef _Float16 half8 __attribute__((ext_vector_type(8)));
typedef float f32x4 __attribute__((ext_vector_type(4)));
typedef __fp16 fp16x2 __attribute__((ext_vector_type(2)));

// K-pair slot tables (p = 4*h + d), chosen so each read instruction's 4
// h-group bank bases (6*ty+tx mod 32) are {a,a+16,b,b+16} -> 2-regular (free).
// p: 0..14 real (ty 0..4, tx 0/2/4), p15 = zero slot (reads base+30, weight 0).
#define TY64 0x11B44891A440ULL      // 3 bits per p
#define TX64 0xF120120120120120ULL  // 4 bits per p, value = tx/2
#define XST 38                      // LDS row stride in dwords; 38 mod 32 = 6

__device__ __forceinline__ float fast_tanh(float x) {
    float e = __expf(2.0f * x);
    return 1.0f - 2.0f / (e + 1.0f);
}
__device__ __forceinline__ unsigned int pkrtz(float a, float b) {
    fp16x2 r = __builtin_amdgcn_cvt_pkrtz(a, b);
    union { fp16x2 h; unsigned int u; } v; v.h = r; return v.u;
}
__device__ __forceinline__ unsigned int pkh(float a, float b) {  // RNE pack
    union { _Float16 h; unsigned short u; } x, y;
    x.h = (_Float16)a; y.h = (_Float16)b;
    return ((unsigned int)y.u << 16) | (unsigned int)x.u;
}
__device__ __forceinline__ void slot(int p, int& ty, int& tx) {
    ty = (int)((TY64 >> (3 * p)) & 7);
    tx = (int)((TX64 >> (4 * p)) & 15) * 2;
}

// ---------------------------------------------------------------------------
// pack conv0/conv1 weights into MFMA A-fragment tables (f16 pairs)
// w0mf: [4h][16oc][4d]   w1mf: [16ic][4h][16oc][4d]
__global__ void pack_weights(const float* __restrict__ c1_w,
                             const float* __restrict__ filters,
                             unsigned int* __restrict__ w0mf,
                             unsigned int* __restrict__ w1mf) {
    int t = blockIdx.x * blockDim.x + threadIdx.x;
    if (t < 256) {
        int d = t & 3, oc = (t >> 2) & 15, hh = (t >> 6) & 3;
        int p = 4 * hh + d, ty, tx; slot(p, ty, tx);
        float lo = 0.f, hi = 0.f;
        if (p != 15) {
            const float* w = filters + oc * 25 + ty * 5 + tx;
            lo = w[0]; hi = (tx < 4) ? w[1] : 0.f;
        }
        w0mf[t] = pkh(lo, hi);
    } else if (t < 256 + 4096) {
        int g = t - 256;
        int d = g & 3, oc = (g >> 2) & 15, hh = (g >> 6) & 3, ic = g >> 8;
        int p = 4 * hh + d, ty, tx; slot(p, ty, tx);
        float lo = 0.f, hi = 0.f;
        if (p != 15 && oc < 6) {
            const float* w = c1_w + (oc * 16 + ic) * 25 + ty * 5 + tx;
            lo = w[0]; hi = (tx < 4) ? w[1] : 0.f;
        }
        w1mf[g] = pkh(lo, hi);
    }
}

// ---------------------------------------------------------------------------
// Fused LeNet: conv0(MFMA)+tanh -> conv1(MFMA)+tanh+pool -> conv3+tanh+pool
// -> c5+tanh -> fc1+tanh -> fc2.  One block = one image, 512 threads.
// LDS ~92 KB -> 1 block/CU (8 waves = 2/SIMD).
__global__ __launch_bounds__(512, 2) void lenet_all(
    const float* __restrict__ x,        // [B,1,32,32]
    const unsigned int* __restrict__ w0mf,
    const unsigned int* __restrict__ w1mf,
    const float* __restrict__ c1_b,
    const float* __restrict__ c3_w, const float* __restrict__ c3_b,
    const float* __restrict__ c5_w, const float* __restrict__ c5_b,
    const float* __restrict__ l1_w, const float* __restrict__ l1_b,
    const float* __restrict__ l2_w, const float* __restrict__ l2_b,
    float* __restrict__ out)            // [B,10]
{
    __shared__ unsigned int xs2[36 * XST];         // padded input, pair-dup f16
    __shared__ unsigned int s1p[512 * XST + 32];   // tanh(conv0), pair-dup f16, +2*oc stagger
    __shared__ float a2[6 * 14 * 18];
    __shared__ float a3[400];
    __shared__ float f5[120];
    __shared__ float f6[84];

    const int b = blockIdx.x;
    const int tid = threadIdx.x;
    const int lane = tid & 63;
    const int wid = tid >> 6;        // 0..7
    const int h = (lane >> 4) & 3;
    const int c = lane & 15;
    const float* xb = x + (size_t)b * 1024;

    // zero-fill (slack regions must be finite: zero-weight slots read them)
    for (int i = tid; i < 36 * XST; i += 512) xs2[i] = 0u;
    for (int i = tid; i < 512 * XST + 32; i += 512) s1p[i] = 0u;

    // resident A-fragments
    half8 af0 = *(const half8*)(w0mf + (h * 16 + c) * 4);
    half8 af[16];
#pragma unroll
    for (int ks = 0; ks < 16; ks++)
        af[ks] = *(const half8*)(w1mf + ((ks * 4 + h) * 16 + c) * 4);

    // per-lane B-read dword offsets (shared by conv0 and conv1)
    int offd[4];
#pragma unroll
    for (int d = 0; d < 4; ++d) {
        int p = 4 * h + d, ty, tx; slot(p, ty, tx);
        offd[d] = ty * XST + tx + c;
    }
    __syncthreads();

    // ---- P0: input -> pair-dup padded f16 LDS.  thread (r, cc): px 2cc,2cc+1
    {
        int r = tid >> 4, cc = tid & 15;
        float2 v = *(const float2*)(xb + r * 32 + cc * 2);
        float vnext = __shfl(v.x, lane + 1);
        if (cc == 15) vnext = 0.f;
        unsigned int d0 = pkrtz(v.x, v.y);
        unsigned int d1 = pkrtz(v.y, vnext);
        unsigned int* row = &xs2[(r + 2) * XST];
        *(uint2*)&row[2 * cc + 2] = make_uint2(d0, d1);
        if (cc == 0) row[1] = pkrtz(0.f, v.x);
    }
    __syncthreads();

    // ---- P1: conv0 via MFMA (64 tiles = 32 rows x 2 halves), tanh epilogue
#pragma unroll 1
    for (int yi = 0; yi < 4; ++yi) {
        const int y = 4 * wid + yi;
        const int base = y * XST;
        union H8 { unsigned int u[4]; half8 hv; };
        H8 B0, B1;
#pragma unroll
        for (int d = 0; d < 4; ++d) {
            B0.u[d] = xs2[base + offd[d]];
            B1.u[d] = xs2[base + 16 + offd[d]];
        }
        f32x4 ac0 = {0.f, 0.f, 0.f, 0.f};
        f32x4 ac1 = {0.f, 0.f, 0.f, 0.f};
        ac0 = __builtin_amdgcn_mfma_f32_16x16x32_f16(af0, B0.hv, ac0, 0, 0, 0);
        ac1 = __builtin_amdgcn_mfma_f32_16x16x32_f16(af0, B1.hv, ac1, 0, 0, 0);
#pragma unroll
        for (int r = 0; r < 4; ++r) {
            int oc = 4 * h + r;
            float t0 = fast_tanh(ac0[r]), t1 = fast_tanh(ac1[r]);
            float t0n = __shfl(t0, lane + 1);
            float t1n = __shfl(t1, lane + 1);
            float tb  = __shfl(t1, lane & 48);
            float n0 = (c < 15) ? t0n : tb;
            float n1 = (c < 15) ? t1n : 0.f;
            int rbase = (oc * 32 + y) * XST + oc * 2;
            s1p[rbase + c]      = pkrtz(t0, n0);
            s1p[rbase + 16 + c] = pkrtz(t1, n1);
        }
    }
    __syncthreads();

    // ---- P2: conv1 via MFMA + bias + tanh + avgpool -> a2 (LDS)
#pragma unroll 1
    for (int q = wid; q < 28; q += 8) {
        const int py = q >> 1;
        const int xh = q & 1;
        const int x0 = 12 * xh;
        const int yy = 2 * py;
        f32x4 ac0 = {0.f, 0.f, 0.f, 0.f};
        f32x4 ac1 = {0.f, 0.f, 0.f, 0.f};
#pragma unroll
        for (int ks = 0; ks < 16; ks++) {
            const int kb = (ks * 32 + yy) * XST + ks * 2 + x0;
            union H8 { unsigned int u[4]; half8 hv; };
            H8 B0, B1;
#pragma unroll
            for (int d = 0; d < 4; ++d) {
                B0.u[d] = s1p[kb + offd[d]];
                B1.u[d] = s1p[kb + XST + offd[d]];
            }
            ac0 = __builtin_amdgcn_mfma_f32_16x16x32_f16(af[ks], B0.hv, ac0, 0, 0, 0);
            ac1 = __builtin_amdgcn_mfma_f32_16x16x32_f16(af[ks], B1.hv, ac1, 0, 0, 0);
        }
#pragma unroll
        for (int r = 0; r < 4; ++r) {
            int oc = 4 * h + r;
            if (oc < 6) {
                float bb = c1_b[oc];
                float t = fast_tanh(ac0[r] + bb) + fast_tanh(ac1[r] + bb);
                t += __shfl_xor(t, 1);
                int pq = (c >> 1) + 6 * xh;
                bool keep = ((c & 1) == 0) && (xh ? (pq >= 7) : (pq <= 6));
                if (keep) a2[(oc * 14 + py) * 18 + pq] = 0.25f * t;
            }
        }
    }
    __syncthreads();

    // ---- P3: conv3 + bias + tanh + pool (400 tasks)
    if (tid < 400) {
        const int oc = tid / 25;
        const int rr = tid % 25;
        const int py = rr / 5, px = rr % 5;
        const int x0 = px * 2, y0 = py * 2;
        float a00 = 0.f, a01 = 0.f, a10 = 0.f, a11 = 0.f;
#pragma unroll 1
        for (int ic = 0; ic < 6; ic++) {
            const float* wr = c3_w + (oc * 6 + ic) * 25;
            float w[25];
#pragma unroll
            for (int qq = 0; qq < 25; qq++) w[qq] = wr[qq];
#pragma unroll
            for (int t6 = 0; t6 < 6; t6++) {
                float seg[6];
                const float2* sp = (const float2*)&a2[(ic * 14 + y0 + t6) * 18 + x0];
#pragma unroll
                for (int qq = 0; qq < 3; qq++) {
                    float2 v = sp[qq];
                    seg[2 * qq] = v.x; seg[2 * qq + 1] = v.y;
                }
                if (t6 < 5) {
#pragma unroll
                    for (int kx = 0; kx < 5; kx++) {
                        float wv = w[t6 * 5 + kx];
                        a00 += wv * seg[kx]; a01 += wv * seg[kx + 1];
                    }
                }
                if (t6 >= 1) {
#pragma unroll
                    for (int kx = 0; kx < 5; kx++) {
                        float wv = w[(t6 - 1) * 5 + kx];
                        a10 += wv * seg[kx]; a11 += wv * seg[kx + 1];
                    }
                }
            }
        }
        const float bb = c3_b[oc];
        a3[tid] = 0.25f * (fast_tanh(a00 + bb) + fast_tanh(a01 + bb) +
                           fast_tanh(a10 + bb) + fast_tanh(a11 + bb));
    }
    __syncthreads();

    // ---- P4: c5 (120 dots over 400; 2 threads/output)
    if (tid < 240) {
        const int o = tid >> 1;
        const int part = tid & 1;
        float acc = 0.0f;
        const float4* wp = (const float4*)(c5_w + (size_t)o * 400) + part * 50;
        const float4* ap = ((const float4*)a3) + part * 50;
#pragma unroll 5
        for (int qq = 0; qq < 50; qq++) {
            float4 wv = wp[qq], av = ap[qq];
            acc += wv.x * av.x + wv.y * av.y + wv.z * av.z + wv.w * av.w;
        }
        acc += __shfl_xor(acc, 1);
        if (part == 0) f5[o] = fast_tanh(acc + c5_b[o]);
    }
    __syncthreads();

    // ---- P5: fc1
    if (tid < 84) {
        float acc = l1_b[tid];
        const float4* wp = (const float4*)(l1_w + tid * 120);
        const float4* fp = (const float4*)f5;
#pragma unroll
        for (int qq = 0; qq < 30; qq++) {
            float4 wv = wp[qq], fv = fp[qq];
            acc += wv.x * fv.x + wv.y * fv.y + wv.z * fv.z + wv.w * fv.w;
        }
        f6[tid] = fast_tanh(acc);
    }
    __syncthreads();

    // ---- P6: fc2
    if (tid < 10) {
        float acc = l2_b[tid];
        const float* wp = l2_w + tid * 84;
#pragma unroll
        for (int qq = 0; qq < 84; qq++) acc += wp[qq] * f6[qq];
        out[(size_t)b * 10 + tid] = acc;
    }
}

extern "C" void kernel_launch(void* const* d_in, const int* in_sizes, int n_in,
                              void* d_out, int out_size, void* d_ws, size_t ws_size,
                              hipStream_t stream) {
    const float* x       = (const float*)d_in[0];
    const float* filters = (const float*)d_in[1];
    const float* c1_w    = (const float*)d_in[2];
    const float* c1_b    = (const float*)d_in[3];
    const float* c3_w    = (const float*)d_in[4];
    const float* c3_b    = (const float*)d_in[5];
    const float* c5_w    = (const float*)d_in[6];
    const float* c5_b    = (const float*)d_in[7];
    const float* l1_w    = (const float*)d_in[8];
    const float* l1_b    = (const float*)d_in[9];
    const float* l2_w    = (const float*)d_in[10];
    const float* l2_b    = (const float*)d_in[11];
    float* out = (float*)d_out;

    const int B = in_sizes[0] / 1024;

    // ws: [w0mf: 256 u32 @0][w1mf: 4096 u32 @1024]
    unsigned int* w0mf = (unsigned int*)d_ws;
    unsigned int* w1mf = (unsigned int*)((char*)d_ws + 1024);

    pack_weights<<<17, 256, 0, stream>>>(c1_w, filters, w0mf, w1mf);
    lenet_all<<<B, 512, 0, stream>>>(x, w0mf, w1mf, c1_b, c3_w, c3_b,
                                     c5_w, c5_b, l1_w, l1_b, l2_w, l2_b, out);
}

// Round 11
// 298.424 us; speedup vs baseline: 1.2594x; 1.2594x over previous
//
#include <hip/hip_runtime.h>
#include <hip/hip_bf16.h>
#include <cstddef>

typedef _Float16 h2 __attribute__((ext_vector_type(2)));
typedef _Float16 half8 __attribute__((ext_vector_type(8)));
typedef float f32x4 __attribute__((ext_vector_type(4)));

__device__ __forceinline__ float fast_tanh(float x) {
    float e = __expf(2.0f * x);
    return 1.0f - 2.0f / (e + 1.0f);
}

__device__ __forceinline__ float fdot2u(unsigned int a, unsigned int b, float c) {
    union U { unsigned int u; h2 h; };
    U ua; ua.u = a;
    U ub; ub.u = b;
    return __builtin_amdgcn_fdot2(ua.h, ub.h, c, false);
}

__device__ __forceinline__ unsigned int pkh(float a, float b) {
    union { _Float16 h; unsigned short u; } x, y;
    x.h = (_Float16)a; y.h = (_Float16)b;
    return ((unsigned int)y.u << 16) | (unsigned int)x.u;
}

// K-slot permutation for conv1 MFMA (K=32 per ic) — round-5 verified:
// pair p (slots 2p,2p+1): p<10: taps (row p>>1, cols 2(p&1), 2(p&1)+1)
//                         p=10..14: (row p-10, col 4) + zero ; p=15: zero,zero
#define S1D 33  // s1p row stride in dwords

// ---------------------------------------------------------------------------
// pack: f0pk (conv0 dot2 pairs) + w1mf (conv1 MFMA A-frags) — round-5 verbatim
__global__ void pack_weights(const float* __restrict__ c1_w,
                             const float* __restrict__ filters,
                             unsigned int* __restrict__ f0pk,   // [16][5][6]
                             unsigned int* __restrict__ w1mf) { // [16ic][4h][16oc][4d]
    int t = blockIdx.x * blockDim.x + threadIdx.x;
    if (t < 80) {
        int oc = t / 5, ky = t % 5;
        const float* w = filters + oc * 25 + ky * 5;
        unsigned int* d = f0pk + oc * 30 + ky * 6;
        d[0] = pkh(w[0], w[1]); d[1] = pkh(w[2], w[3]); d[2] = pkh(w[4], 0.f);
        d[3] = pkh(0.f, w[0]); d[4] = pkh(w[1], w[2]); d[5] = pkh(w[3], w[4]);
    } else if (t >= 256 && t < 256 + 4096) {
        int g = t - 256;
        int d = g & 3, oc = (g >> 2) & 15, h = (g >> 6) & 3, ic = g >> 8;
        int p = 4 * h + d;
        float w0 = 0.f, w1 = 0.f;
        if (oc < 6) {
            const float* w = c1_w + (oc * 16 + ic) * 25;
            if (p < 10) {
                int ty = p >> 1, txb = 2 * (p & 1);
                w0 = w[ty * 5 + txb]; w1 = w[ty * 5 + txb + 1];
            } else if (p < 15) {
                w0 = w[(p - 10) * 5 + 4];
            }
        }
        w1mf[g] = pkh(w0, w1);
    }
}

// ---------------------------------------------------------------------------
// Kernel A (round-5 math, 512-thread schedule): conv0 dot2 + tanh -> pair-dup
// f16 LDS; conv1 via MFMA 16x16x32_f16 + bias + tanh + avgpool2 -> out2.
// LDS: s1p 67584 B + xs2 2736 B = 70320 B -> 2 blocks/CU, 16 waves/CU.
__global__ __launch_bounds__(512, 2) void lenet_front(
    const float* __restrict__ x,            // [B,1,32,32]
    const unsigned int* __restrict__ f0pk,
    const unsigned int* __restrict__ w1mf,
    const float* __restrict__ c1_b,         // [6]
    float* __restrict__ out2)               // [B,6,14,14]
{
    __shared__ unsigned int xs2[36 * 19];       // padded input, f16 pairs
    __shared__ unsigned int s1p[16 * 32 * S1D]; // tanh(conv0): dword x = (px x, px x+1)

    const int b = blockIdx.x;
    const int tid = threadIdx.x;
    const float* xb = x + (size_t)b * 1024;

    for (int i = tid; i < 36 * 19; i += 512) xs2[i] = 0u;
    __syncthreads();
    // P0: one element per thread (512 = 32 rows x 16 pair-cols)
    {
        int r = tid >> 4, c2 = tid & 15;
        const float2 v = *(const float2*)(xb + r * 32 + c2 * 2);
        xs2[(r + 2) * 19 + c2 + 1] = pkh(v.x, v.y);
    }
    __syncthreads();

    // ---- Phase A: conv0 + tanh, 5 px/thread, pair-dup dwords.
    // 256 (y,xg) tasks x 2 oc-halves (tid>>8 selects oc 0..7 / 8..15).
    {
        const int tt = tid & 255;
        const int y = tt >> 3;
        const int xg = tt & 7;
        const int x0 = xg * 4;
        const int x0h = xg * 2;
        const int oc0 = (tid >> 8) * 8;
        unsigned int win2[5][5];
#pragma unroll
        for (int i = 0; i < 5; i++) {
            const unsigned int* pr = &xs2[(y + i) * 19 + x0h];
#pragma unroll
            for (int q = 0; q < 5; q++) win2[i][q] = pr[q];
        }
#pragma unroll 1
        for (int oc = oc0; oc < oc0 + 8; oc++) {
            const unsigned int* fw = f0pk + oc * 30;  // uniform -> s_load
            float a0 = 0.f, a1 = 0.f, a2 = 0.f, a3 = 0.f, a4 = 0.f;
#pragma unroll
            for (int ky = 0; ky < 5; ky++) {
                unsigned int w01 = fw[ky * 6 + 0], w23 = fw[ky * 6 + 1], w4z = fw[ky * 6 + 2];
                unsigned int zw0 = fw[ky * 6 + 3], w12 = fw[ky * 6 + 4], w34 = fw[ky * 6 + 5];
                a0 = fdot2u(w01, win2[ky][0], a0);
                a0 = fdot2u(w23, win2[ky][1], a0);
                a0 = fdot2u(w4z, win2[ky][2], a0);
                a1 = fdot2u(zw0, win2[ky][0], a1);
                a1 = fdot2u(w12, win2[ky][1], a1);
                a1 = fdot2u(w34, win2[ky][2], a1);
                a2 = fdot2u(w01, win2[ky][1], a2);
                a2 = fdot2u(w23, win2[ky][2], a2);
                a2 = fdot2u(w4z, win2[ky][3], a2);
                a3 = fdot2u(zw0, win2[ky][1], a3);
                a3 = fdot2u(w12, win2[ky][2], a3);
                a3 = fdot2u(w34, win2[ky][3], a3);
                a4 = fdot2u(w01, win2[ky][2], a4);
                a4 = fdot2u(w23, win2[ky][3], a4);
                a4 = fdot2u(w4z, win2[ky][4], a4);
            }
            float t0 = fast_tanh(a0), t1 = fast_tanh(a1), t2 = fast_tanh(a2);
            float t3 = fast_tanh(a3), t4 = fast_tanh(a4);
            int base = (oc * 32 + y) * S1D + x0;
            s1p[base + 0] = pkh(t0, t1);
            s1p[base + 1] = pkh(t1, t2);
            s1p[base + 2] = pkh(t2, t3);
            s1p[base + 3] = pkh(t3, t4);
        }
    }
    __syncthreads();

    // ---- Phase B (round-5 verbatim, 8-wave schedule): conv1 MFMA + epilogue
    const int lane = tid & 63;
    const int wid = tid >> 6;        // 0..7
    const int h = lane >> 4;
    const int c = lane & 15;

    half8 af[16];
    const half8* w1v = (const half8*)w1mf;
#pragma unroll
    for (int ks = 0; ks < 16; ks++) af[ks] = w1v[(ks * 4 + h) * 16 + c];

    int offd[4];
#pragma unroll
    for (int pl = 0; pl < 4; pl++) {
        int p = 4 * h + pl;
        int pp = (p < 15) ? p : 14;
        int ty = (pp < 10) ? (pp >> 1) : (pp - 10);
        int tx = (pp < 10) ? ((pp & 1) * 2) : 4;
        offd[pl] = ty * S1D + tx + c;
    }

    float bias_l[4];
#pragma unroll
    for (int r = 0; r < 4; r++) {
        int rr = 4 * h + r;
        bias_l[r] = c1_b[rr < 6 ? rr : 5];
    }

#pragma unroll 1
    for (int q = wid; q < 28; q += 8) {
        const int py = q >> 1;
        const int xh = q & 1;
        const int x0 = 12 * xh;
        const int yy = 2 * py;

        f32x4 acc0 = {0.f, 0.f, 0.f, 0.f};
        f32x4 acc1 = {0.f, 0.f, 0.f, 0.f};
#pragma unroll
        for (int ks = 0; ks < 16; ks++) {
            const int bb0 = (ks * 32 + yy) * S1D + x0;
            union H8 { unsigned int u[4]; half8 hv; };
            H8 B0, B1;
#pragma unroll
            for (int pl = 0; pl < 4; pl++) {
                B0.u[pl] = s1p[bb0 + offd[pl]];
                B1.u[pl] = s1p[bb0 + S1D + offd[pl]];
            }
            acc0 = __builtin_amdgcn_mfma_f32_16x16x32_f16(af[ks], B0.hv, acc0, 0, 0, 0);
            acc1 = __builtin_amdgcn_mfma_f32_16x16x32_f16(af[ks], B1.hv, acc1, 0, 0, 0);
        }
#pragma unroll
        for (int r = 0; r < 4; r++) {
            int rr = 4 * h + r;
            float t = fast_tanh(acc0[r] + bias_l[r]) + fast_tanh(acc1[r] + bias_l[r]);
            t += __shfl_xor(t, 1);
            int pq = (c >> 1) + 6 * xh;
            bool ok = (rr < 6) && ((c & 1) == 0) && (xh ? (pq >= 7) : (pq <= 6));
            if (ok) out2[((size_t)b * 6 + rr) * 196 + py * 14 + pq] = 0.25f * t;
        }
    }
}

// ---------------------------------------------------------------------------
// Kernel B (round-5 verbatim): conv3+tanh+pool -> c5+tanh -> fc1+tanh -> fc2
__global__ __launch_bounds__(256) void lenet_back(
    const float* __restrict__ out2,  // [B,6,14,14]
    const float* __restrict__ c3_w,  // [16,6,5,5]
    const float* __restrict__ c3_b,  // [16]
    const float* __restrict__ c5_w,  // [120,16,5,5]
    const float* __restrict__ c5_b,  // [120]
    const float* __restrict__ l1_w,  // [84,120]
    const float* __restrict__ l1_b,  // [84]
    const float* __restrict__ l2_w,  // [10,84]
    const float* __restrict__ l2_b,  // [10]
    float* __restrict__ out)         // [B,10]
{
    __shared__ float a2[6 * 14 * 18];
    __shared__ float a3[400];
    __shared__ float f5[120];
    __shared__ float f6[84];

    const int b = blockIdx.x;
    const int tid = threadIdx.x;

    for (int i = tid; i < 1176; i += 256) {
        int row = i / 14, c = i % 14;
        a2[row * 18 + c] = out2[(size_t)b * 1176 + i];
    }
    __syncthreads();

    for (int t = tid; t < 400; t += 256) {
        const int oc = t / 25;
        const int rr = t % 25;
        const int py = rr / 5, px = rr % 5;
        const int x0 = px * 2, y0 = py * 2;
        float a00 = 0.f, a01 = 0.f, a10 = 0.f, a11 = 0.f;
#pragma unroll 1
        for (int ic = 0; ic < 6; ic++) {
            const float* wr = c3_w + (oc * 6 + ic) * 25;
            float w[25];
#pragma unroll
            for (int q = 0; q < 25; q++) w[q] = wr[q];
#pragma unroll
            for (int t6 = 0; t6 < 6; t6++) {
                float seg[6];
                const float2* sp = (const float2*)&a2[(ic * 14 + y0 + t6) * 18 + x0];
#pragma unroll
                for (int q = 0; q < 3; q++) {
                    float2 v = sp[q];
                    seg[2 * q] = v.x; seg[2 * q + 1] = v.y;
                }
                if (t6 < 5) {
#pragma unroll
                    for (int kx = 0; kx < 5; kx++) {
                        float wv = w[t6 * 5 + kx];
                        a00 += wv * seg[kx]; a01 += wv * seg[kx + 1];
                    }
                }
                if (t6 >= 1) {
#pragma unroll
                    for (int kx = 0; kx < 5; kx++) {
                        float wv = w[(t6 - 1) * 5 + kx];
                        a10 += wv * seg[kx]; a11 += wv * seg[kx + 1];
                    }
                }
            }
        }
        const float bb = c3_b[oc];
        a3[t] = 0.25f * (fast_tanh(a00 + bb) + fast_tanh(a01 + bb) +
                         fast_tanh(a10 + bb) + fast_tanh(a11 + bb));
    }
    __syncthreads();

    if (tid < 240) {
        const int o = tid >> 1;
        const int part = tid & 1;
        float acc = 0.0f;
        const float4* wp = (const float4*)(c5_w + (size_t)o * 400) + part * 50;
        const float4* ap = ((const float4*)a3) + part * 50;
#pragma unroll 5
        for (int q = 0; q < 50; q++) {
            float4 wv = wp[q], av = ap[q];
            acc += wv.x * av.x + wv.y * av.y + wv.z * av.z + wv.w * av.w;
        }
        acc += __shfl_xor(acc, 1);
        if (part == 0) f5[o] = fast_tanh(acc + c5_b[o]);
    }
    __syncthreads();

    if (tid < 84) {
        float acc = l1_b[tid];
        const float4* wp = (const float4*)(l1_w + tid * 120);
        const float4* fp = (const float4*)f5;
#pragma unroll
        for (int q = 0; q < 30; q++) {
            float4 wv = wp[q], fv = fp[q];
            acc += wv.x * fv.x + wv.y * fv.y + wv.z * fv.z + wv.w * fv.w;
        }
        f6[tid] = fast_tanh(acc);
    }
    __syncthreads();

    if (tid < 10) {
        float acc = l2_b[tid];
        const float* wp = l2_w + tid * 84;
#pragma unroll
        for (int q = 0; q < 84; q++) acc += wp[q] * f6[q];
        out[(size_t)b * 10 + tid] = acc;
    }
}

extern "C" void kernel_launch(void* const* d_in, const int* in_sizes, int n_in,
                              void* d_out, int out_size, void* d_ws, size_t ws_size,
                              hipStream_t stream) {
    const float* x       = (const float*)d_in[0];
    const float* filters = (const float*)d_in[1];
    const float* c1_w    = (const float*)d_in[2];
    const float* c1_b    = (const float*)d_in[3];
    const float* c3_w    = (const float*)d_in[4];
    const float* c3_b    = (const float*)d_in[5];
    const float* c5_w    = (const float*)d_in[6];
    const float* c5_b    = (const float*)d_in[7];
    const float* l1_w    = (const float*)d_in[8];
    const float* l1_b    = (const float*)d_in[9];
    const float* l2_w    = (const float*)d_in[10];
    const float* l2_b    = (const float*)d_in[11];
    float* out = (float*)d_out;

    const int B = in_sizes[0] / 1024;

    // ws layout: [f0pk: 480 u32 @0, 2048 B][w1mf: 4096 u32 @2048, 16384 B][out2 @18432]
    unsigned int* f0pk = (unsigned int*)d_ws;
    unsigned int* w1mf = (unsigned int*)((char*)d_ws + 2048);
    float* out2 = (float*)((char*)d_ws + 18432);

    pack_weights<<<17, 256, 0, stream>>>(c1_w, filters, f0pk, w1mf);
    lenet_front<<<B, 512, 0, stream>>>(x, f0pk, w1mf, c1_b, out2);
    lenet_back<<<B, 256, 0, stream>>>(out2, c3_w, c3_b, c5_w, c5_b,
                                      l1_w, l1_b, l2_w, l2_b, out);
}